// Round 19
// baseline (183.429 us; speedup 1.0000x reference)
//
#include <hip/hip_runtime.h>

#define NN 50000
#define NE 800000
#define FIN 512
#define FHID 256
#define FOUT 128
#define MPAD 50048  // 782 * 64

#define TW1_BLOCKS  512     // FIN*FHID/256
#define TW2_BLOCKS  128     // FHID*FOUT/256

// Two-level bucket sort
#define NBKT   196          // coarse bucket = dst >> 8
#define BCAP   5120         // slots/bucket: mean 4082 + 16 sigma
#define BSTRIDE 16          // bcur counter stride (ints) -> one 64B line each
#define PA_BLOCKS 392
#define E_CHA    2048       // 392 * 2048 = 802816 >= NE
#define PB_BLOCKS 196

using bf16x8 = __attribute__((ext_vector_type(8))) short;
using f32x4  = __attribute__((ext_vector_type(4))) float;
using u16x8  = __attribute__((ext_vector_type(8))) unsigned short;

__device__ __forceinline__ unsigned short f2bf(float f) {
    unsigned int u = __builtin_bit_cast(unsigned int, f);
    unsigned int r = (u + 0x7FFFu + ((u >> 16) & 1u)) >> 16;   // RNE
    return (unsigned short)r;
}
__device__ __forceinline__ float bf2f(unsigned short u) {
    return __builtin_bit_cast(float, (unsigned int)u << 16);
}
__device__ __forceinline__ void gload_lds16(const void* g, void* l) {
    __builtin_amdgcn_global_load_lds(
        (const __attribute__((address_space(1))) void*)g,
        (__attribute__((address_space(3))) void*)l, 16, 0, 0);
}

// ---- k1: passA (bucket bin) || transpose W1 || transpose W2 ----

__global__ __launch_bounds__(256) void fused_passa_prep_kernel(
    const int* __restrict__ src, const int* __restrict__ dst,
    const float* __restrict__ w, int* __restrict__ bcur, int2* __restrict__ barr,
    const float* __restrict__ W1, unsigned short* __restrict__ W1T,
    const float* __restrict__ W2, unsigned short* __restrict__ W2T) {
    int b = blockIdx.x, tid = threadIdx.x;
    if (b < PA_BLOCKS) {
        __shared__ int hist[NBKT];
        __shared__ int resv[NBKT];
        if (tid < NBKT) hist[tid] = 0;
        __syncthreads();
        int base = b * E_CHA + tid;
        int  d[8];
        bool m[8];
#pragma unroll
        for (int j = 0; j < 8; ++j) {
            int e = base + j * 256;
            m[j] = e < NE;
            d[j] = m[j] ? dst[e] : 0;
        }
#pragma unroll
        for (int j = 0; j < 8; ++j)
            if (m[j]) atomicAdd(&hist[d[j] >> 8], 1);
        __syncthreads();
        if (tid < NBKT) {
            int h = hist[tid];
            resv[tid] = (h > 0) ? atomicAdd(&bcur[tid * BSTRIDE], h) : 0;
            hist[tid] = 0;  // reuse as rank counter
        }
        __syncthreads();
        int   s[8];
        float wv[8];
#pragma unroll
        for (int j = 0; j < 8; ++j) {
            int e = base + j * 256;
            s[j]  = m[j] ? src[e] : 0;
            wv[j] = m[j] ? w[e] : 0.f;
        }
#pragma unroll
        for (int j = 0; j < 8; ++j) {
            if (m[j]) {
                int bb = d[j] >> 8;
                int r  = atomicAdd(&hist[bb], 1);
                int pos = resv[bb] + r;
                if (pos < BCAP)
                    barr[(size_t)bb * BCAP + pos] =
                        make_int2(s[j] | ((d[j] & 255) << 16), __float_as_int(wv[j]));
            }
        }
    } else if (b < PA_BLOCKS + TW1_BLOCKS) {
        int t = (b - PA_BLOCKS) * 256 + tid;
        int n = t % FHID, k = t / FHID;
        W1T[(size_t)n * FIN + k] = f2bf(W1[t]);
    } else {
        int t = (b - PA_BLOCKS - TW1_BLOCKS) * 256 + tid;
        int n = t % FOUT, k = t / FOUT;
        W2T[(size_t)n * FHID + k] = f2bf(W2[t]);
    }
}

// ---- GEMM1 body: BARRIER-FREE K-loop. A staged ONCE (64x512 bf16 = 64KB LDS,
// XOR-swizzled, one barrier); B fragments read directly from L2-resident W1T
// (no staging, no per-K barrier). 16 K-steps of pure {global-B, ds-A, MFMA}. ----

__device__ __forceinline__ void gemm1_body(const float* __restrict__ X,
                                           const unsigned short* __restrict__ BT,
                                           unsigned short* __restrict__ C,
                                           int bx) {
    __shared__ unsigned short As[64 * 512];   // 64 KB

    const int tid  = threadIdx.x;
    const int lane = tid & 63;
    const int wv   = tid >> 6;                // 0..3; wave owns output cols wv*64..+63
    const int brow = bx * 64;
    const int r15   = lane & 15;
    const int khalf = (lane >> 4) * 8;

    // ---- stage A once: 64 rows x 512 cols; thread handles 16 chunks of 8 elems ----
#pragma unroll
    for (int g = 0; g < 16; ++g) {
        int idx  = g * 256 + tid;             // 0..4095
        int row  = idx >> 6;                  // 0..63
        int col0 = (idx & 63) * 8;            // 0..504
        int grow = min(brow + row, NN - 1);   // clamp: pad rows never stored
        const float4* p = (const float4*)(X + (size_t)grow * FIN + col0);
        float4 a0 = p[0], a1 = p[1];
        u16x8 v;
        v[0] = f2bf(a0.x); v[1] = f2bf(a0.y); v[2] = f2bf(a0.z); v[3] = f2bf(a0.w);
        v[4] = f2bf(a1.x); v[5] = f2bf(a1.y); v[6] = f2bf(a1.z); v[7] = f2bf(a1.w);
        int byte = row * 1024 + ((col0 * 2) ^ ((row & 7) << 4));
        *(u16x8*)((char*)As + byte) = v;
    }
    __syncthreads();   // the ONLY barrier

    f32x4 acc[4][4] = {};
#pragma unroll
    for (int ks = 0; ks < 16; ++ks) {
        // B fragments straight from global W1T (L2-resident, 256 KB)
        bf16x8 bfr[4];
#pragma unroll
        for (int n = 0; n < 4; ++n) {
            int wrow = wv * 64 + n * 16 + r15;
            bfr[n] = *(const bf16x8*)(BT + (size_t)wrow * FIN + ks * 32 + khalf);
        }
        // A fragments from swizzled LDS
        bf16x8 af[4];
#pragma unroll
        for (int m = 0; m < 4; ++m) {
            int row  = m * 16 + r15;
            int byte = row * 1024 + (((ks * 32 + khalf) * 2) ^ ((row & 7) << 4));
            af[m] = *(const bf16x8*)((const char*)As + byte);
        }
#pragma unroll
        for (int m = 0; m < 4; ++m)
#pragma unroll
            for (int n = 0; n < 4; ++n)
                acc[m][n] = __builtin_amdgcn_mfma_f32_16x16x32_bf16(
                    af[m], bfr[n], acc[m][n], 0, 0, 0);
    }

    const int rsub = (lane >> 4) * 4;
#pragma unroll
    for (int m = 0; m < 4; ++m) {
#pragma unroll
        for (int r = 0; r < 4; ++r) {
            int grow = brow + m * 16 + rsub + r;
            if (grow < NN) {
#pragma unroll
                for (int n = 0; n < 4; ++n)
                    C[(size_t)grow * FHID + wv * 64 + n * 16 + r15] = f2bf(acc[m][n][r]);
            }
        }
    }
}

// ---- passB body (self-scan, 256 threads, r17-proven) ----

__device__ __forceinline__ void passb_body(const int2* __restrict__ barr,
                                           const int* __restrict__ bcur,
                                           int* __restrict__ off,
                                           int2* __restrict__ csr) {
    __shared__ int sc[256];
    __shared__ int cnt[256];
    __shared__ int pre[256];
    __shared__ int wsum[4];
    int b = blockIdx.x, tid = threadIdx.x, lane = tid & 63, wid = tid >> 6;

    int v = (tid < NBKT) ? min(bcur[tid * BSTRIDE], BCAP) : 0;
    int s = v;
#pragma unroll
    for (int d = 1; d < 64; d <<= 1) {
        int t = __shfl_up(s, d, 64);
        if (lane >= d) s += t;
    }
    if (lane == 63) wsum[wid] = s;
    __syncthreads();
    int wo = 0;
#pragma unroll
    for (int j = 0; j < 4; ++j)
        if (j < wid) wo += wsum[j];
    sc[tid] = wo + s - v;
    if (b == 0 && tid == NBKT - 1) off[NN] = wo + s;
    cnt[tid] = 0;
    __syncthreads();

    int bko_b = sc[b];
    int total = min(bcur[b * BSTRIDE], BCAP);
    const int2* seg = barr + (size_t)b * BCAP;

    for (int k = tid; k < total; k += 256)
        atomicAdd(&cnt[(seg[k].x >> 16) & 255], 1);
    __syncthreads();
    int v2 = cnt[tid];
    int s2 = v2;
#pragma unroll
    for (int d = 1; d < 64; d <<= 1) {
        int t = __shfl_up(s2, d, 64);
        if (lane >= d) s2 += t;
    }
    if (lane == 63) wsum[wid] = s2;
    __syncthreads();
    int wo2 = 0;
#pragma unroll
    for (int j = 0; j < 4; ++j)
        if (j < wid) wo2 += wsum[j];
    int base = bko_b + wo2 + s2 - v2;
    pre[tid] = base;
    int n = b * 256 + tid;
    if (n < NN) off[n] = base;
    cnt[tid] = 0;
    __syncthreads();
    for (int k = tid; k < total; k += 256) {
        int2 pl = seg[k];
        int dlow = (pl.x >> 16) & 255;
        int r = atomicAdd(&cnt[dlow], 1);
        csr[pre[dlow] + r] = make_int2(pl.x & 0xFFFF, pl.y);
    }
}

// ---- k2: passB || gemm1 (barrier-free) ----

__global__ __launch_bounds__(256) void fused_passb_gemm1_kernel(
    const int2* __restrict__ barr, const int* __restrict__ bcur,
    int* __restrict__ off, int2* __restrict__ csr,
    const float* __restrict__ X, const unsigned short* __restrict__ BT,
    unsigned short* __restrict__ C) {
    if (blockIdx.x < PB_BLOCKS) {
        passb_body(barr, bcur, off, csr);
    } else {
        gemm1_body(X, BT, C, blockIdx.x - PB_BLOCKS);
    }
}

// ---- k3: pull-SpMM layer 1: 2 nodes per wave, u16x8 loads (at vmem ceiling) ----

__global__ __launch_bounds__(256) void spmm_pair_kernel(const unsigned short* __restrict__ X,
                                                        const int* __restrict__ off,
                                                        const int2* __restrict__ csr,
                                                        unsigned short* __restrict__ Y) {
    int wave = (int)((blockIdx.x * 256 + threadIdx.x) >> 6);
    int lane = threadIdx.x & 63;
    int half = lane >> 5;
    int hl   = lane & 31;
    int n = wave * 2 + half;
    if (n >= NN) return;
    int e0 = off[n];
    int e1 = off[n + 1];

    float acc[8] = {};
    for (int e = e0; e < e1; e += 8) {
        unsigned ssb[8];
        float    ww[8];
#pragma unroll
        for (int j = 0; j < 8; ++j) {
            int  ee = e + j;
            bool v  = ee < e1;
            int2 sw = csr[v ? ee : e0];
            ssb[j] = (unsigned)(sw.x * (FHID * 2));   // 32-bit byte offset
            ww[j]  = v ? __int_as_float(sw.y) : 0.f;
        }
        u16x8 r[8];
#pragma unroll
        for (int j = 0; j < 8; ++j)
            r[j] = *(const u16x8*)((const char*)X + ssb[j] + hl * 16);
#pragma unroll
        for (int j = 0; j < 8; ++j)
#pragma unroll
            for (int k = 0; k < 8; ++k)
                acc[k] += ww[j] * bf2f(r[j][k]);
    }
    u16x8 o;
#pragma unroll
    for (int k = 0; k < 8; ++k) o[k] = f2bf(fmaxf(acc[k], 0.f));
    *(u16x8*)(Y + (size_t)n * FHID + (size_t)hl * 8) = o;
}

// ---- k4: GEMM2 standalone: 64x128 full-N tile, BK=64 ----

__global__ __launch_bounds__(256) void gemm2_kernel(const unsigned short* __restrict__ A,
                                                    const unsigned short* __restrict__ BT,
                                                    unsigned short* __restrict__ C) {
    __shared__ unsigned short As[64 * 64];    // 8 KB
    __shared__ unsigned short Bs[128 * 64];   // 16 KB

    const int tid  = threadIdx.x;
    const int lane = tid & 63;
    const int wid  = tid >> 6;
    const int brow = blockIdx.x * 64;
    const int r15   = lane & 15;
    const int khalf = (lane >> 4) * 8;

    f32x4 acc[4][2] = {};

#pragma unroll
    for (int k = 0; k < 4; ++k) {
        const int k0 = k * 64;
#pragma unroll
        for (int c = 0; c < 4; ++c) {
            int b   = wid * 4096 + c * 1024 + lane * 16;
            int row = b >> 7;
            int cby = (b & 127) ^ ((row & 7) << 4);
            const char* gb = (const char*)(BT + (size_t)row * FHID + k0) + cby;
            gload_lds16(gb, (char*)Bs + wid * 4096 + c * 1024);
        }
#pragma unroll
        for (int c = 0; c < 2; ++c) {
            int b   = wid * 2048 + c * 1024 + lane * 16;
            int row = b >> 7;
            int cby = (b & 127) ^ ((row & 7) << 4);
            const char* ga = (const char*)(A + (size_t)(brow + row) * FHID + k0) + cby;
            gload_lds16(ga, (char*)As + wid * 2048 + c * 1024);
        }
        __syncthreads();

        bf16x8 bfr[2][2];
#pragma unroll
        for (int n = 0; n < 2; ++n) {
            int row = wid * 32 + n * 16 + r15;
            int rb  = row * 128;
            int sw  = (row & 7) << 4;
#pragma unroll
            for (int ks = 0; ks < 2; ++ks)
                bfr[n][ks] = *(const bf16x8*)((const char*)Bs + rb + (((ks * 32 + khalf) * 2) ^ sw));
        }
#pragma unroll
        for (int m = 0; m < 4; ++m) {
            int row = m * 16 + r15;
            int rb  = row * 128;
            int sw  = (row & 7) << 4;
            bf16x8 af0 = *(const bf16x8*)((const char*)As + rb + (((0 + khalf) * 2) ^ sw));
            bf16x8 af1 = *(const bf16x8*)((const char*)As + rb + (((32 + khalf) * 2) ^ sw));
#pragma unroll
            for (int n = 0; n < 2; ++n) {
                acc[m][n] = __builtin_amdgcn_mfma_f32_16x16x32_bf16(af0, bfr[n][0], acc[m][n], 0, 0, 0);
                acc[m][n] = __builtin_amdgcn_mfma_f32_16x16x32_bf16(af1, bfr[n][1], acc[m][n], 0, 0, 0);
            }
        }
        __syncthreads();
    }

    const int rsub = (lane >> 4) * 4;
#pragma unroll
    for (int m = 0; m < 4; ++m) {
#pragma unroll
        for (int r = 0; r < 4; ++r) {
            int grow = brow + m * 16 + rsub + r;
            if (grow < NN) {
#pragma unroll
                for (int n = 0; n < 2; ++n)
                    C[(size_t)grow * FOUT + wid * 32 + n * 16 + r15] = f2bf(acc[m][n][r]);
            }
        }
    }
}

// ---- k5: pull-SpMM layer 2: 4 nodes per wave (16-lane quarters), f32 out ----

__global__ __launch_bounds__(256) void spmm_quad_kernel(const unsigned short* __restrict__ X,
                                                        const int* __restrict__ off,
                                                        const int2* __restrict__ csr,
                                                        float* __restrict__ Y) {
    int wave = (int)((blockIdx.x * 256 + threadIdx.x) >> 6);
    int lane = threadIdx.x & 63;
    int q  = lane >> 4;
    int hl = lane & 15;
    int n = wave * 4 + q;
    if (n >= NN) return;
    int e0 = off[n];
    int e1 = off[n + 1];

    float acc[8] = {};
    for (int e = e0; e < e1; e += 8) {
        unsigned ssb[8];
        float    ww[8];
#pragma unroll
        for (int j = 0; j < 8; ++j) {
            int  ee = e + j;
            bool v  = ee < e1;
            int2 sw = csr[v ? ee : e0];
            ssb[j] = (unsigned)(sw.x * (FOUT * 2));   // 32-bit byte offset
            ww[j]  = v ? __int_as_float(sw.y) : 0.f;
        }
        u16x8 r[8];
#pragma unroll
        for (int j = 0; j < 8; ++j)
            r[j] = *(const u16x8*)((const char*)X + ssb[j] + hl * 16);
#pragma unroll
        for (int j = 0; j < 8; ++j)
#pragma unroll
            for (int k = 0; k < 8; ++k)
                acc[k] += ww[j] * bf2f(r[j][k]);
    }
    float4 o0 = make_float4(acc[0], acc[1], acc[2], acc[3]);
    float4 o1 = make_float4(acc[4], acc[5], acc[6], acc[7]);
    *(float4*)(Y + (size_t)n * FOUT + hl * 8) = o0;
    *(float4*)(Y + (size_t)n * FOUT + hl * 8 + 4) = o1;
}

// ---------------- launch ----------------

extern "C" void kernel_launch(void* const* d_in, const int* in_sizes, int n_in,
                              void* d_out, int out_size, void* d_ws, size_t ws_size,
                              hipStream_t stream) {
    const float* features = (const float*)d_in[0];
    const int*   edge_src = (const int*)d_in[1];
    const int*   edge_dst = (const int*)d_in[2];
    const float* edge_w   = (const float*)d_in[3];
    const float* W1       = (const float*)d_in[4];
    const float* W2       = (const float*)d_in[5];
    float* out = (float*)d_out;

    char*  ws  = (char*)d_ws;
    size_t ofs = 0;
    auto carve = [&](size_t bytes) -> void* {
        void* r = ws + ofs;
        ofs = (ofs + bytes + 255) & ~(size_t)255;
        return r;
    };
    int*            off   = (int*)carve((NN + 1) * sizeof(int));
    int*            bcur  = (int*)carve(NBKT * BSTRIDE * sizeof(int));
    int2*           barr  = (int2*)carve((size_t)NBKT * BCAP * sizeof(int2));
    int2*           csr   = (int2*)carve((size_t)NE * sizeof(int2));
    unsigned short* W1T   = (unsigned short*)carve((size_t)FHID * FIN * 2);
    unsigned short* W2T   = (unsigned short*)carve((size_t)FOUT * FHID * 2);
    unsigned short* H0b   = (unsigned short*)carve((size_t)MPAD * FHID * 2);
    unsigned short* Hb    = (unsigned short*)carve((size_t)MPAD * FHID * 2);
    unsigned short* H1b   = H0b;  // H0b dead after spmm1

    hipMemsetAsync(bcur, 0, NBKT * BSTRIDE * sizeof(int), stream);

    // k1: passA (bucket bin) || transpose W1 || transpose W2
    fused_passa_prep_kernel<<<PA_BLOCKS + TW1_BLOCKS + TW2_BLOCKS, 256, 0, stream>>>(
        edge_src, edge_dst, edge_w, bcur, barr, W1, W1T, W2, W2T);

    // k2: passB (off/csr) || gemm1 (H0 = X @ W1, barrier-free K-loop)
    fused_passb_gemm1_kernel<<<PB_BLOCKS + MPAD / 64, 256, 0, stream>>>(
        barr, bcur, off, csr, features, W1T, H0b);

    // k3: hidden = relu(A @ H0)  (bf16) — 2 nodes/wave, split (max gather TLP)
    spmm_pair_kernel<<<6250, 256, 0, stream>>>(H0b, off, csr, Hb);

    // k4: H1 = hidden @ W2 (64x128 full-N)
    gemm2_kernel<<<MPAD / 64, 256, 0, stream>>>(Hb, W2T, H1b);

    // k5: out = A @ H1 — 4 nodes/wave
    spmm_quad_kernel<<<3125, 256, 0, stream>>>(H1b, off, csr, out);
}

// Round 20
// 168.013 us; speedup vs baseline: 1.0918x; 1.0918x over previous
//
#include <hip/hip_runtime.h>

#define NN 50000
#define NE 800000
#define FIN 512
#define FHID 256
#define FOUT 128
#define MPAD 50048  // 782 * 64

#define TW1_BLOCKS  512     // FIN*FHID/256
#define TW2_BLOCKS  128     // FHID*FOUT/256
#define ZERO_BLOCKS 13      // 13*256 >= NBKT*BSTRIDE

// Two-level bucket sort
#define NBKT   196          // coarse bucket = dst >> 8  (49999>>8 = 195)
#define BCAP   5120         // slots/bucket: mean 4082, sigma~64 -> +16 sigma
#define BSTRIDE 16          // bcur counter stride (ints) -> one 64B line each
#define PA_BLOCKS 392
#define E_CHA    2048       // 392 * 2048 = 802816 >= NE

#define PB_BLOCKS    196    // pass B: one block per bucket
#define GEMM1_BLOCKS 1564   // 782 M-tiles x 2 N-tiles (64x128)
#define GEMM2_BLOCKS 782    // 782 M-tiles x 1 N-tile  (64x128)

using bf16x8 = __attribute__((ext_vector_type(8))) short;
using f32x4  = __attribute__((ext_vector_type(4))) float;
using u16x8  = __attribute__((ext_vector_type(8))) unsigned short;

__device__ __forceinline__ unsigned short f2bf(float f) {
    unsigned int u = __builtin_bit_cast(unsigned int, f);
    unsigned int r = (u + 0x7FFFu + ((u >> 16) & 1u)) >> 16;   // RNE
    return (unsigned short)r;
}
__device__ __forceinline__ float bf2f(unsigned short u) {
    return __builtin_bit_cast(float, (unsigned int)u << 16);
}
__device__ __forceinline__ void gload_lds16(const void* g, void* l) {
    __builtin_amdgcn_global_load_lds(
        (const __attribute__((address_space(1))) void*)g,
        (__attribute__((address_space(3))) void*)l, 16, 0, 0);
}

// ---- prep: zero bcur || transpose W1 || transpose W2 ----

__global__ __launch_bounds__(256) void prep_kernel(
    int* __restrict__ bcur,
    const float* __restrict__ W1, unsigned short* __restrict__ W1T,
    const float* __restrict__ W2, unsigned short* __restrict__ W2T) {
    int b = blockIdx.x, tid = threadIdx.x;
    if (b < TW1_BLOCKS) {
        int t = b * 256 + tid;
        int n = t % FHID, k = t / FHID;
        W1T[(size_t)n * FIN + k] = f2bf(W1[t]);
    } else if (b < TW1_BLOCKS + TW2_BLOCKS) {
        int t = (b - TW1_BLOCKS) * 256 + tid;
        int n = t % FOUT, k = t / FOUT;
        W2T[(size_t)n * FHID + k] = f2bf(W2[t]);
    } else {
        int i = (b - TW1_BLOCKS - TW2_BLOCKS) * 256 + tid;
        if (i < NBKT * BSTRIDE) bcur[i] = 0;
    }
}

// ---- pass A: bin edges into 196 coarse buckets (LDS hist, 1 global atomic per
// (block,bucket) reservation; 8-wide MLP; dst kept in registers) ----

__device__ __forceinline__ void passa_body(int pa,
                                           const int* __restrict__ src,
                                           const int* __restrict__ dst,
                                           const float* __restrict__ w,
                                           int* __restrict__ bcur,
                                           int2* __restrict__ barr) {
    __shared__ int hist[NBKT];
    __shared__ int resv[NBKT];
    int tid = threadIdx.x;
    if (tid < NBKT) hist[tid] = 0;
    __syncthreads();
    int base = pa * E_CHA + tid;
    int  d[8];
    bool m[8];
#pragma unroll
    for (int j = 0; j < 8; ++j) {
        int e = base + j * 256;
        m[j] = e < NE;
        d[j] = m[j] ? dst[e] : 0;
    }
#pragma unroll
    for (int j = 0; j < 8; ++j)
        if (m[j]) atomicAdd(&hist[d[j] >> 8], 1);
    __syncthreads();
    if (tid < NBKT) {
        int h = hist[tid];
        resv[tid] = (h > 0) ? atomicAdd(&bcur[tid * BSTRIDE], h) : 0;
        hist[tid] = 0;  // reuse as rank counter
    }
    __syncthreads();
    int   s[8];
    float wv[8];
#pragma unroll
    for (int j = 0; j < 8; ++j) {
        int e = base + j * 256;
        s[j]  = m[j] ? src[e] : 0;
        wv[j] = m[j] ? w[e] : 0.f;
    }
#pragma unroll
    for (int j = 0; j < 8; ++j) {
        if (m[j]) {
            int bb = d[j] >> 8;
            int r  = atomicAdd(&hist[bb], 1);
            int pos = resv[bb] + r;
            if (pos < BCAP)
                barr[(size_t)bb * BCAP + pos] =
                    make_int2(s[j] | ((d[j] & 255) << 16), __float_as_int(wv[j]));
        }
    }
}

// ---- GEMM1 body: 64x128 tile, BK=64, 4 waves (2x2: 32x64 each), A staged
// directly from f32 X (reg cast -> swizzled ds_write), B via global_load_lds ----

__device__ __forceinline__ void gemm1_body(const float* __restrict__ X,
                                           const unsigned short* __restrict__ BT,
                                           unsigned short* __restrict__ C,
                                           int bx, int by) {
    __shared__ unsigned short As[64 * 64];    // 8 KB
    __shared__ unsigned short Bs[128 * 64];   // 16 KB

    const int tid  = threadIdx.x;
    const int lane = tid & 63;
    const int wid  = tid >> 6;
    const int wm   = wid >> 1;
    const int wn   = wid & 1;
    const int brow = bx * 64;
    const int bcol = by * 128;
    const int r15   = lane & 15;
    const int khalf = (lane >> 4) * 8;

    f32x4 acc[2][4] = {};

    for (int k0 = 0; k0 < FIN; k0 += 64) {
        // B staging (16 KB, 4x1KB per wave)
#pragma unroll
        for (int c = 0; c < 4; ++c) {
            int b   = wid * 4096 + c * 1024 + lane * 16;
            int row = b >> 7;
            int cby = (b & 127) ^ ((row & 7) << 4);
            const char* gb = (const char*)(BT + (size_t)(bcol + row) * FIN + k0) + cby;
            gload_lds16(gb, (char*)Bs + wid * 4096 + c * 1024);
        }
        // A staging (8 KB): f32 load -> bf16 cast -> swizzled ds_write
#pragma unroll
        for (int g = 0; g < 2; ++g) {
            int idx  = g * 256 + tid;       // 0..511 chunks of 8 elements
            int row  = idx >> 3;            // 0..63
            int col0 = (idx & 7) * 8;
            float4 a0 = make_float4(0.f, 0.f, 0.f, 0.f), a1 = a0;
            int grow = brow + row;
            if (grow < NN) {
                const float4* p = (const float4*)(X + (size_t)grow * FIN + k0 + col0);
                a0 = p[0]; a1 = p[1];
            }
            u16x8 v;
            v[0] = f2bf(a0.x); v[1] = f2bf(a0.y); v[2] = f2bf(a0.z); v[3] = f2bf(a0.w);
            v[4] = f2bf(a1.x); v[5] = f2bf(a1.y); v[6] = f2bf(a1.z); v[7] = f2bf(a1.w);
            int byte = row * 128 + ((col0 * 2) ^ ((row & 7) << 4));
            *(u16x8*)((char*)As + byte) = v;
        }
        __syncthreads();

        bf16x8 af[2][2], bfr[4][2];
#pragma unroll
        for (int m = 0; m < 2; ++m) {
            int row = wm * 32 + m * 16 + r15;
            int rb  = row * 128;
            int sw  = (row & 7) << 4;
#pragma unroll
            for (int ks = 0; ks < 2; ++ks) {
                int byte = rb + (((ks * 32 + khalf) * 2) ^ sw);
                af[m][ks] = *(const bf16x8*)((const char*)As + byte);
            }
        }
#pragma unroll
        for (int n = 0; n < 4; ++n) {
            int row = wn * 64 + n * 16 + r15;
            int rb  = row * 128;
            int sw  = (row & 7) << 4;
#pragma unroll
            for (int ks = 0; ks < 2; ++ks) {
                int byte = rb + (((ks * 32 + khalf) * 2) ^ sw);
                bfr[n][ks] = *(const bf16x8*)((const char*)Bs + byte);
            }
        }
#pragma unroll
        for (int m = 0; m < 2; ++m)
#pragma unroll
            for (int n = 0; n < 4; ++n)
#pragma unroll
                for (int ks = 0; ks < 2; ++ks)
                    acc[m][n] = __builtin_amdgcn_mfma_f32_16x16x32_bf16(
                        af[m][ks], bfr[n][ks], acc[m][n], 0, 0, 0);
        __syncthreads();
    }

    const int crow0 = brow + wm * 32;
    const int ccol0 = bcol + wn * 64 + r15;
    const int rsub  = (lane >> 4) * 4;
#pragma unroll
    for (int m = 0; m < 2; ++m) {
#pragma unroll
        for (int r = 0; r < 4; ++r) {
            int grow = crow0 + m * 16 + rsub + r;
            if (grow < NN) {
#pragma unroll
                for (int n = 0; n < 4; ++n)
                    C[(size_t)grow * FHID + ccol0 + n * 16] = f2bf(acc[m][n][r]);
            }
        }
    }
}

// ---- fused: passA (first, critical path to passB) || gemm1 ----

__global__ __launch_bounds__(256) void fused_passa_gemm1_kernel(
    const int* __restrict__ src, const int* __restrict__ dst,
    const float* __restrict__ w, int* __restrict__ bcur, int2* __restrict__ barr,
    const float* __restrict__ X, const unsigned short* __restrict__ BT,
    unsigned short* __restrict__ C) {
    if (blockIdx.x < PA_BLOCKS) {
        passa_body(blockIdx.x, src, dst, w, bcur, barr);
    } else {
        int g = blockIdx.x - PA_BLOCKS;
        gemm1_body(X, BT, C, g >> 1, g & 1);   // adjacent blocks share the X row-slice
    }
}

// ---- pass B with SELF-SCAN: each block computes the 196-bucket exclusive scan
// (replaces the scan kernel), then LDS-histograms dst&255, writes off[] slice,
// and places edges into the bucket's contiguous csr region. ----

__global__ __launch_bounds__(256) void passb_kernel(const int2* __restrict__ barr,
                                                    const int* __restrict__ bcur,
                                                    int* __restrict__ off,
                                                    int2* __restrict__ csr) {
    __shared__ int sc[256];
    __shared__ int cnt[256];
    __shared__ int pre[256];
    __shared__ int wsum[4];
    int b = blockIdx.x, tid = threadIdx.x, lane = tid & 63, wid = tid >> 6;

    // self-scan of bucket totals
    int v = (tid < NBKT) ? min(bcur[tid * BSTRIDE], BCAP) : 0;
    int s = v;
#pragma unroll
    for (int d = 1; d < 64; d <<= 1) {
        int t = __shfl_up(s, d, 64);
        if (lane >= d) s += t;
    }
    if (lane == 63) wsum[wid] = s;
    __syncthreads();
    int wo = 0;
#pragma unroll
    for (int j = 0; j < 4; ++j)
        if (j < wid) wo += wsum[j];
    sc[tid] = wo + s - v;
    if (b == 0 && tid == NBKT - 1) off[NN] = wo + s;   // total
    cnt[tid] = 0;
    __syncthreads();

    int bko_b = sc[b];
    int total = min(bcur[b * BSTRIDE], BCAP);
    const int2* seg = barr + (size_t)b * BCAP;

    // phase 1: count by low-8 dst
    for (int k = tid; k < total; k += 256)
        atomicAdd(&cnt[(seg[k].x >> 16) & 255], 1);
    __syncthreads();
    // phase 2: per-node prefix -> absolute csr base; write off slice
    int v2 = cnt[tid];
    int s2 = v2;
#pragma unroll
    for (int d = 1; d < 64; d <<= 1) {
        int t = __shfl_up(s2, d, 64);
        if (lane >= d) s2 += t;
    }
    if (lane == 63) wsum[wid] = s2;
    __syncthreads();
    int wo2 = 0;
#pragma unroll
    for (int j = 0; j < 4; ++j)
        if (j < wid) wo2 += wsum[j];
    int base = bko_b + wo2 + s2 - v2;
    pre[tid] = base;
    int n = b * 256 + tid;
    if (n < NN) off[n] = base;
    cnt[tid] = 0;  // reuse as rank counter
    __syncthreads();
    // phase 3: place
    for (int k = tid; k < total; k += 256) {
        int2 pl = seg[k];
        int dlow = (pl.x >> 16) & 255;
        int r = atomicAdd(&cnt[dlow], 1);
        csr[pre[dlow] + r] = make_int2(pl.x & 0xFFFF, pl.y);
    }
}

// ---- GEMM2: 64x128 tile (full N=128), BK=64, bf16 A via global_load_lds ----

__global__ __launch_bounds__(256) void gemm2_kernel(const unsigned short* __restrict__ A,
                                                    const unsigned short* __restrict__ BT,
                                                    unsigned short* __restrict__ C) {
    __shared__ unsigned short As[64 * 64];
    __shared__ unsigned short Bs[128 * 64];

    const int tid  = threadIdx.x;
    const int lane = tid & 63;
    const int wid  = tid >> 6;
    const int wm   = wid >> 1;
    const int wn   = wid & 1;
    const int brow = blockIdx.x * 64;
    const int r15   = lane & 15;
    const int khalf = (lane >> 4) * 8;

    f32x4 acc[2][4] = {};

    for (int k0 = 0; k0 < FHID; k0 += 64) {
        // B staging (16 KB, 4x1KB per wave)
#pragma unroll
        for (int c = 0; c < 4; ++c) {
            int b   = wid * 4096 + c * 1024 + lane * 16;
            int row = b >> 7;
            int cby = (b & 127) ^ ((row & 7) << 4);
            const char* gb = (const char*)(BT + (size_t)row * FHID + k0) + cby;
            gload_lds16(gb, (char*)Bs + wid * 4096 + c * 1024);
        }
        // A staging (8 KB, 2x1KB per wave)
#pragma unroll
        for (int c = 0; c < 2; ++c) {
            int b   = wid * 2048 + c * 1024 + lane * 16;
            int row = b >> 7;
            int cby = (b & 127) ^ ((row & 7) << 4);
            const char* ga = (const char*)(A + (size_t)(brow + row) * FHID + k0) + cby;
            gload_lds16(ga, (char*)As + wid * 2048 + c * 1024);
        }
        __syncthreads();

        bf16x8 af[2][2], bfr[4][2];
#pragma unroll
        for (int m = 0; m < 2; ++m) {
            int row = wm * 32 + m * 16 + r15;
            int rb  = row * 128;
            int sw  = (row & 7) << 4;
#pragma unroll
            for (int ks = 0; ks < 2; ++ks) {
                int byte = rb + (((ks * 32 + khalf) * 2) ^ sw);
                af[m][ks] = *(const bf16x8*)((const char*)As + byte);
            }
        }
#pragma unroll
        for (int n = 0; n < 4; ++n) {
            int row = wn * 64 + n * 16 + r15;
            int rb  = row * 128;
            int sw  = (row & 7) << 4;
#pragma unroll
            for (int ks = 0; ks < 2; ++ks) {
                int byte = rb + (((ks * 32 + khalf) * 2) ^ sw);
                bfr[n][ks] = *(const bf16x8*)((const char*)Bs + byte);
            }
        }
#pragma unroll
        for (int m = 0; m < 2; ++m)
#pragma unroll
            for (int n = 0; n < 4; ++n)
#pragma unroll
                for (int ks = 0; ks < 2; ++ks)
                    acc[m][n] = __builtin_amdgcn_mfma_f32_16x16x32_bf16(
                        af[m][ks], bfr[n][ks], acc[m][n], 0, 0, 0);
        __syncthreads();
    }

    const int crow0 = brow + wm * 32;
    const int ccol0 = wn * 64 + r15;
    const int rsub  = (lane >> 4) * 4;
#pragma unroll
    for (int m = 0; m < 2; ++m) {
#pragma unroll
        for (int r = 0; r < 4; ++r) {
            int grow = crow0 + m * 16 + rsub + r;
            if (grow < NN) {
#pragma unroll
                for (int n = 0; n < 4; ++n)
                    C[(size_t)grow * FOUT + ccol0 + n * 16] = f2bf(acc[m][n][r]);
            }
        }
    }
}

// ---- pull-SpMM layer 1: 2 nodes per wave (32-lane halves), u16x8 lane loads ----

__global__ __launch_bounds__(256) void spmm_pair_kernel(const unsigned short* __restrict__ X,
                                                        const int* __restrict__ off,
                                                        const int2* __restrict__ csr,
                                                        unsigned short* __restrict__ Y) {
    int wave = (int)((blockIdx.x * 256 + threadIdx.x) >> 6);
    int lane = threadIdx.x & 63;
    int half = lane >> 5;
    int hl   = lane & 31;
    int n = wave * 2 + half;
    if (n >= NN) return;
    int e0 = off[n];
    int e1 = off[n + 1];
    const size_t fo = (size_t)hl * 8;

    float acc[8] = {};
    for (int e = e0; e < e1; e += 8) {
        int   ss[8];
        float ww[8];
#pragma unroll
        for (int j = 0; j < 8; ++j) {
            int  ee = e + j;
            bool v  = ee < e1;
            int2 sw = csr[v ? ee : e0];
            ss[j] = sw.x;
            ww[j] = v ? __int_as_float(sw.y) : 0.f;
        }
        u16x8 r[8];
#pragma unroll
        for (int j = 0; j < 8; ++j)
            r[j] = *(const u16x8*)(X + (size_t)ss[j] * FHID + fo);
#pragma unroll
        for (int j = 0; j < 8; ++j)
#pragma unroll
            for (int k = 0; k < 8; ++k)
                acc[k] += ww[j] * bf2f(r[j][k]);
    }
    u16x8 o;
#pragma unroll
    for (int k = 0; k < 8; ++k) o[k] = f2bf(fmaxf(acc[k], 0.f));
    *(u16x8*)(Y + (size_t)n * FHID + fo) = o;
}

// ---- pull-SpMM layer 2: 4 nodes per wave (16-lane quarters), f32 output ----

__global__ __launch_bounds__(256) void spmm_quad_kernel(const unsigned short* __restrict__ X,
                                                        const int* __restrict__ off,
                                                        const int2* __restrict__ csr,
                                                        float* __restrict__ Y) {
    int wave = (int)((blockIdx.x * 256 + threadIdx.x) >> 6);
    int lane = threadIdx.x & 63;
    int q  = lane >> 4;
    int hl = lane & 15;
    int n = wave * 4 + q;
    if (n >= NN) return;
    int e0 = off[n];
    int e1 = off[n + 1];
    const size_t fo = (size_t)hl * 8;

    float acc[8] = {};
    for (int e = e0; e < e1; e += 8) {
        int   ss[8];
        float ww[8];
#pragma unroll
        for (int j = 0; j < 8; ++j) {
            int  ee = e + j;
            bool v  = ee < e1;
            int2 sw = csr[v ? ee : e0];
            ss[j] = sw.x;
            ww[j] = v ? __int_as_float(sw.y) : 0.f;
        }
        u16x8 r[8];
#pragma unroll
        for (int j = 0; j < 8; ++j)
            r[j] = *(const u16x8*)(X + (size_t)ss[j] * FOUT + fo);
#pragma unroll
        for (int j = 0; j < 8; ++j)
#pragma unroll
            for (int k = 0; k < 8; ++k)
                acc[k] += ww[j] * bf2f(r[j][k]);
    }
    float4 o0 = make_float4(acc[0], acc[1], acc[2], acc[3]);
    float4 o1 = make_float4(acc[4], acc[5], acc[6], acc[7]);
    *(float4*)(Y + (size_t)n * FOUT + fo) = o0;
    *(float4*)(Y + (size_t)n * FOUT + fo + 4) = o1;
}

// ---------------- launch ----------------

extern "C" void kernel_launch(void* const* d_in, const int* in_sizes, int n_in,
                              void* d_out, int out_size, void* d_ws, size_t ws_size,
                              hipStream_t stream) {
    const float* features = (const float*)d_in[0];
    const int*   edge_src = (const int*)d_in[1];
    const int*   edge_dst = (const int*)d_in[2];
    const float* edge_w   = (const float*)d_in[3];
    const float* W1       = (const float*)d_in[4];
    const float* W2       = (const float*)d_in[5];
    float* out = (float*)d_out;

    char*  ws  = (char*)d_ws;
    size_t ofs = 0;
    auto carve = [&](size_t bytes) -> void* {
        void* r = ws + ofs;
        ofs = (ofs + bytes + 255) & ~(size_t)255;
        return r;
    };
    int*            off   = (int*)carve((NN + 1) * sizeof(int));
    int*            bcur  = (int*)carve(NBKT * BSTRIDE * sizeof(int));
    int2*           barr  = (int2*)carve((size_t)NBKT * BCAP * sizeof(int2));
    int2*           csr   = (int2*)carve((size_t)NE * sizeof(int2));
    unsigned short* W1T   = (unsigned short*)carve((size_t)FHID * FIN * 2);
    unsigned short* W2T   = (unsigned short*)carve((size_t)FOUT * FHID * 2);
    unsigned short* H0b   = (unsigned short*)carve((size_t)MPAD * FHID * 2);
    unsigned short* Hb    = (unsigned short*)carve((size_t)MPAD * FHID * 2);
    unsigned short* H1b   = H0b;  // H0b dead after spmm1

    // prep: transposes + zero bcur
    prep_kernel<<<TW1_BLOCKS + TW2_BLOCKS + ZERO_BLOCKS, 256, 0, stream>>>(
        bcur, W1, W1T, W2, W2T);

    // passA (bucket bin) || gemm1 (H0 = X @ W1, 64x128 tiles, direct f32 A)
    fused_passa_gemm1_kernel<<<PA_BLOCKS + GEMM1_BLOCKS, 256, 0, stream>>>(
        edge_src, edge_dst, edge_w, bcur, barr, features, W1T, H0b);

    // passB with self-scan: off[] + csr placement
    passb_kernel<<<PB_BLOCKS, 256, 0, stream>>>(barr, bcur, off, csr);

    // hidden = relu(A @ H0)  (bf16) — 2 nodes/wave
    spmm_pair_kernel<<<6250, 256, 0, stream>>>(H0b, off, csr, Hb);

    // H1 = hidden @ W2 (64x128 tiles) ; out = A @ H1 — 4 nodes/wave
    gemm2_kernel<<<GEMM2_BLOCKS, 256, 0, stream>>>(Hb, W2T, H1b);
    spmm_quad_kernel<<<3125, 256, 0, stream>>>(H1b, off, csr, out);
}